// Round 3
// baseline (883.993 us; speedup 1.0000x reference)
//
#include <hip/hip_runtime.h>
#include <hip/hip_bf16.h>

// N=12288, D=256.
//   e[i,j] = lrelu(u[i] + v[j]);  u = h_eu@a1 + h_lo@a3, v = h_po@a2
//   q = exp(e - 25) masked by adj>0   (constant shift; exp is scale-free)
//   out_i = (0.5*deg_i/denom_i) * (q_i @ h_po) + 0.5 * (adj_i @ h_po)
// u,v are pre-scaled by log2e so the kernel uses a single v_exp_f32 (exp2).
//
// fused2: barrier-free main loop. Waves split (rowfrag x kslice); each lane
// computes its own MFMA A-fragment in registers (R=1), accumulates full D=256
// (16 dt x 2 mats = 128 acc VGPRs), one-time LDS reduce over kslices at end.

#define NN 12288
#define DD 256
#define BM 32
#define STEPS (NN / 64)   // 192 macro-steps of BK=64
#define LOG2E 1.44269504f
#define SHIFT2 36.067376f  // 25*log2e

typedef __attribute__((ext_vector_type(8))) short s16x8;
typedef __attribute__((ext_vector_type(4))) float f32x4;

__device__ __forceinline__ unsigned short f2bf(float f) {
  unsigned u = __builtin_bit_cast(unsigned, f);
  u += 0x7FFFu + ((u >> 16) & 1u);
  return (unsigned short)(u >> 16);
}
__device__ __forceinline__ unsigned pack_bf2(float a, float b) {
  unsigned short lo = __builtin_bit_cast(unsigned short, __float2bfloat16(a));
  unsigned short hi = __builtin_bit_cast(unsigned short, __float2bfloat16(b));
  return (unsigned)lo | ((unsigned)hi << 16);
}
__device__ __forceinline__ float exp2_hw(float x) {
  float r;
  asm("v_exp_f32 %0, %1" : "=v"(r) : "v"(x));
  return r;
}

// ---------------- prep: u2 = (h_eu@a1 + h_lo@a3)*log2e, v2 = (h_po@a2)*log2e --
__global__ __launch_bounds__(256) void prep_uv(
    const float* __restrict__ h_eu, const float* __restrict__ h_po,
    const float* __restrict__ h_lo, const float* __restrict__ a1,
    const float* __restrict__ a2, const float* __restrict__ a3,
    float* __restrict__ u, float* __restrict__ v) {
  const int t = threadIdx.x;
  const int wave = t >> 6, lane = t & 63;
  const int r0 = blockIdx.x * 64;
  for (int rr = 0; rr < 16; ++rr) {
    const int row = r0 + wave * 16 + rr;
    const float* pe = h_eu + (size_t)row * DD;
    const float* pl = h_lo + (size_t)row * DD;
    const float* pp = h_po + (size_t)row * DD;
    float su = 0.f, sv = 0.f;
#pragma unroll
    for (int c = 0; c < 4; ++c) {
      const int d = lane + c * 64;
      su = fmaf(pe[d], a1[d], su);
      su = fmaf(pl[d], a3[d], su);
      sv = fmaf(pp[d], a2[d], sv);
    }
#pragma unroll
    for (int m = 32; m; m >>= 1) {
      su += __shfl_xor(su, m, 64);
      sv += __shfl_xor(sv, m, 64);
    }
    if (lane == 0) { u[row] = su * LOG2E; v[row] = sv * LOG2E; }
  }
}

// ---------------- prep: h_poT (bf16, [D][N]) ----------------
__global__ __launch_bounds__(256) void prep_T(
    const float* __restrict__ hpo, unsigned short* __restrict__ h_poT) {
  const int t = threadIdx.x;
  const int r0 = blockIdx.x * 64;
  unsigned short* dst = h_poT + (size_t)t * NN + r0;
#pragma unroll
  for (int c = 0; c < 16; ++c) {
    unsigned short x0 = f2bf(hpo[(size_t)(r0 + c * 4 + 0) * DD + t]);
    unsigned short x1 = f2bf(hpo[(size_t)(r0 + c * 4 + 1) * DD + t]);
    unsigned short x2 = f2bf(hpo[(size_t)(r0 + c * 4 + 2) * DD + t]);
    unsigned short x3 = f2bf(hpo[(size_t)(r0 + c * 4 + 3) * DD + t]);
    ((uint2*)dst)[c] = make_uint2((unsigned)x0 | ((unsigned)x1 << 16),
                                  (unsigned)x2 | ((unsigned)x3 << 16));
  }
}

// ---------------- fused2: barrier-free reg-fragment kernel ----------------
__global__ __launch_bounds__(256, 2) void fused2(
    const float* __restrict__ adj, const float* __restrict__ u2,
    const float* __restrict__ v2, const unsigned short* __restrict__ h_poT,
    float* __restrict__ out) {
  __shared__ float vlds[NN];  // 48 KB: v2 staged; reused as reduce buffer after loop
  __shared__ float denom_s[BM], deg_s[BM], coef_s[BM];

  const int t = threadIdx.x;
  const int wave = t >> 6, lane = t & 63;
  const int rf = wave & 1;       // row-fragment: rows rf*16..+16
  const int ks = wave >> 1;      // k-slice: k j+ks*32..+32
  const int lrow = lane & 15, kgrp = lane >> 4;
  const int i0 = blockIdx.x * BM;
  const int row = i0 + rf * 16 + lrow;

  // stage v2 -> LDS, zero stats
  for (int c = t * 4; c < NN; c += 1024)
    *(float4*)&vlds[c] = *(const float4*)&v2[c];
  if (t < BM) { denom_s[t] = 0.f; deg_s[t] = 0.f; }
  __syncthreads();

  const float u_r = u2[row];

  const char* ap = (const char*)adj;
  const char* hpdt[16];
#pragma unroll
  for (int dt = 0; dt < 16; ++dt)
    hpdt[dt] = (const char*)h_poT + (size_t)dt * (16 * NN * 2);  // uniform -> SGPR

  const unsigned aoff0 = (unsigned)row * (NN * 4) + (unsigned)(ks * 128 + kgrp * 32);
  unsigned boff = (unsigned)(lrow * (NN * 2)) + (unsigned)(ks * 64 + kgrp * 16);
  int kvi = ks * 32 + kgrp * 8;

  f32x4 acc1[16] = {};  // q   @ B
  f32x4 acc2[16] = {};  // adj @ B
  float qsum = 0.f, asum = 0.f;

  float4 A0 = *(const float4*)(ap + aoff0);
  float4 A1 = *(const float4*)(ap + aoff0 + 16);
  unsigned ao_next = aoff0;

  auto STEP = [&](float4& C0, float4& C1, float4& X0, float4& X1, bool last) {
    // B loads for THIS step first (so their vmcnt waits don't include adj)
    uint4 b[16];
#pragma unroll
    for (int dt = 0; dt < 16; ++dt)
      b[dt] = *(const uint4*)(hpdt[dt] + boff);
    // prefetch NEXT step's adj (wrap to start on last step: loaded, never used)
    ao_next = last ? aoff0 : ao_next + 256;
    X0 = *(const float4*)(ap + ao_next);
    X1 = *(const float4*)(ap + ao_next + 16);
    // v for this step (LDS)
    const float4 V0 = *(const float4*)&vlds[kvi];
    const float4 V1 = *(const float4*)&vlds[kvi + 4];

    // score 8 elements (this lane's A-fragment row)
    const float cf[8] = {C0.x, C0.y, C0.z, C0.w, C1.x, C1.y, C1.z, C1.w};
    const float vf[8] = {V0.x, V0.y, V0.z, V0.w, V1.x, V1.y, V1.z, V1.w};
    unsigned qp[4], app[4];
#pragma unroll
    for (int e = 0; e < 8; e += 2) {
      const float t0 = u_r + vf[e], t1 = u_r + vf[e + 1];
      const float x0 = fmaxf(t0, 0.01f * t0), x1 = fmaxf(t1, 0.01f * t1);
      float q0 = exp2_hw(x0 - SHIFT2), q1 = exp2_hw(x1 - SHIFT2);
      q0 = (cf[e] > 0.f) ? q0 : 0.f;
      q1 = (cf[e + 1] > 0.f) ? q1 : 0.f;
      qsum += q0; qsum += q1;
      asum += cf[e]; asum += cf[e + 1];
      qp[e >> 1] = pack_bf2(q0, q1);
      app[e >> 1] = pack_bf2(cf[e], cf[e + 1]);
    }
    const s16x8 qa = __builtin_bit_cast(s16x8, *(uint4*)qp);
    const s16x8 aa = __builtin_bit_cast(s16x8, *(uint4*)app);

#pragma unroll
    for (int dt = 0; dt < 16; ++dt) {
      const s16x8 bb = __builtin_bit_cast(s16x8, b[dt]);
      acc1[dt] = __builtin_amdgcn_mfma_f32_16x16x32_bf16(qa, bb, acc1[dt], 0, 0, 0);
      acc2[dt] = __builtin_amdgcn_mfma_f32_16x16x32_bf16(aa, bb, acc2[dt], 0, 0, 0);
    }
    kvi += 64;
    boff += 128;
  };

  float4 N0, N1;
  for (int jt = 0; jt < STEPS; jt += 2) {
    STEP(A0, A1, N0, N1, jt + 1 == STEPS);
    STEP(N0, N1, A0, A1, jt + 2 == STEPS);
  }

  // ---- stats: reduce over kgrp, then LDS-atomic over the 2 kslices ----
  qsum += __shfl_xor(qsum, 16, 64); qsum += __shfl_xor(qsum, 32, 64);
  asum += __shfl_xor(asum, 16, 64); asum += __shfl_xor(asum, 32, 64);
  if (kgrp == 0) {
    atomicAdd(&denom_s[rf * 16 + lrow], qsum);
    atomicAdd(&deg_s[rf * 16 + lrow], asum);
  }
  __syncthreads();  // vlds free; stats complete
  if (t < BM) {
    const float dn = denom_s[t];
    coef_s[t] = dn > 0.f ? 0.5f * deg_s[t] / dn : 0.f;
  }

  // ---- reduce acc over kslices via LDS (reuse vlds region) ----
  float* lred = vlds;  // [2][16][64][4] f32 = 32 KB
  const int lbase = ((rf * 16) * 64 + lane) * 4;
  if (ks == 1) {
#pragma unroll
    for (int dt = 0; dt < 16; ++dt)
      *(f32x4*)&lred[lbase + dt * 256] = acc1[dt];
  }
  __syncthreads();
  if (ks == 0) {
#pragma unroll
    for (int dt = 0; dt < 16; ++dt)
      acc1[dt] += *(const f32x4*)&lred[lbase + dt * 256];
  }
  __syncthreads();
  if (ks == 1) {
#pragma unroll
    for (int dt = 0; dt < 16; ++dt)
      *(f32x4*)&lred[lbase + dt * 256] = acc2[dt];
  }
  __syncthreads();
  if (ks == 0) {
#pragma unroll
    for (int dt = 0; dt < 16; ++dt) {
      acc2[dt] += *(const f32x4*)&lred[lbase + dt * 256];
      const int col = dt * 16 + lrow;
#pragma unroll
      for (int g = 0; g < 4; ++g) {
        const int r = rf * 16 + kgrp * 4 + g;
        out[(size_t)(i0 + r) * DD + col] =
            coef_s[r] * acc1[dt][g] + 0.5f * acc2[dt][g];
      }
    }
  }
}

// ---------------- fallback (small ws): round-2 proven kernel, exp2-adapted ----
template <bool WS_B>
__global__ __launch_bounds__(256) void fused_kernel(
    const float* __restrict__ adj, const float* __restrict__ u,
    const float* __restrict__ v, const unsigned short* __restrict__ h_poT,
    const float* __restrict__ hpo, float* __restrict__ out) {
#define LDA 40
  __shared__ unsigned short qlds[BM][LDA];
  __shared__ unsigned short alds[BM][LDA];
  __shared__ unsigned short bt[WS_B ? 1 : DD][LDA];
  __shared__ float denom_s[BM], deg_s[BM], coef_s[BM];

  const int t = threadIdx.x;
  const int wave = t >> 6, lane = t & 63;
  const int i0 = blockIdx.x * BM;
  const int sr = t >> 3;
  const int sc = (t & 7) * 4;
  const float u_r = u[i0 + sr];
  const int d0 = wave * 64;
  const int lrow = lane & 15;
  const int kgrp = lane >> 4;

  f32x4 acc1[2][4] = {};
  f32x4 acc2[2][4] = {};
  float qsum = 0.f, asum = 0.f;

  const float* arow = adj + (size_t)(i0 + sr) * NN + sc;
  const unsigned short* bptr[4];
  if constexpr (WS_B) {
#pragma unroll
    for (int dt = 0; dt < 4; ++dt)
      bptr[dt] = h_poT + (size_t)(d0 + dt * 16 + lrow) * NN + kgrp * 8;
  }
  float4 a_cur = *(const float4*)(arow);
  uint4 b_cur[4];
  if constexpr (WS_B) {
#pragma unroll
    for (int dt = 0; dt < 4; ++dt) b_cur[dt] = *(const uint4*)(bptr[dt]);
  }

  constexpr int NSTEP = NN / 32;
  for (int jt = 0; jt < NSTEP; ++jt) {
    const int j = jt * 32;
    float4 a_nxt;
    uint4 b_nxt[4];
    const bool has_next = (jt + 1 < NSTEP);
    if (has_next) {
      a_nxt = *(const float4*)(arow + j + 32);
      if constexpr (WS_B) {
#pragma unroll
        for (int dt = 0; dt < 4; ++dt)
          b_nxt[dt] = *(const uint4*)(bptr[dt] + j + 32);
      }
    }
    const float4 vv = *(const float4*)(v + j + sc);
    unsigned short qb[4], ab[4];
    {
      const float aa4[4] = {a_cur.x, a_cur.y, a_cur.z, a_cur.w};
      const float vvv[4] = {vv.x, vv.y, vv.z, vv.w};
#pragma unroll
      for (int k = 0; k < 4; ++k) {
        const float a = aa4[k];
        const float s = u_r + vvv[k];
        const float x = fmaxf(s, 0.01f * s);
        const float q = (a > 0.f) ? exp2_hw(x - SHIFT2) : 0.f;
        qsum += q;
        asum += a;
        qb[k] = f2bf(q);
        ab[k] = f2bf(a);
      }
    }
    *(uint2*)&qlds[sr][sc] = make_uint2((unsigned)qb[0] | ((unsigned)qb[1] << 16),
                                        (unsigned)qb[2] | ((unsigned)qb[3] << 16));
    *(uint2*)&alds[sr][sc] = make_uint2((unsigned)ab[0] | ((unsigned)ab[1] << 16),
                                        (unsigned)ab[2] | ((unsigned)ab[3] << 16));
    if constexpr (!WS_B) {
      const int br = t >> 3;
      const float* src = hpo + (size_t)(j + br) * DD;
#pragma unroll
      for (int cc = 0; cc < 8; ++cc) {
        const int c = (t & 7) * 4 + cc * 32;
        const float4 hv = *(const float4*)(src + c);
        bt[c + 0][br] = f2bf(hv.x);
        bt[c + 1][br] = f2bf(hv.y);
        bt[c + 2][br] = f2bf(hv.z);
        bt[c + 3][br] = f2bf(hv.w);
      }
    }
    __syncthreads();

    const s16x8 qa0 = *(const s16x8*)&qlds[lrow][kgrp * 8];
    const s16x8 qa1 = *(const s16x8*)&qlds[16 + lrow][kgrp * 8];
    const s16x8 ad0 = *(const s16x8*)&alds[lrow][kgrp * 8];
    const s16x8 ad1 = *(const s16x8*)&alds[16 + lrow][kgrp * 8];
#pragma unroll
    for (int dt = 0; dt < 4; ++dt) {
      s16x8 b;
      if constexpr (WS_B)
        b = __builtin_bit_cast(s16x8, b_cur[dt]);
      else
        b = *(const s16x8*)&bt[d0 + dt * 16 + lrow][kgrp * 8];
      acc1[0][dt] = __builtin_amdgcn_mfma_f32_16x16x32_bf16(qa0, b, acc1[0][dt], 0, 0, 0);
      acc1[1][dt] = __builtin_amdgcn_mfma_f32_16x16x32_bf16(qa1, b, acc1[1][dt], 0, 0, 0);
      acc2[0][dt] = __builtin_amdgcn_mfma_f32_16x16x32_bf16(ad0, b, acc2[0][dt], 0, 0, 0);
      acc2[1][dt] = __builtin_amdgcn_mfma_f32_16x16x32_bf16(ad1, b, acc2[1][dt], 0, 0, 0);
    }
    __syncthreads();
    if (has_next) {
      a_cur = a_nxt;
      if constexpr (WS_B) {
#pragma unroll
        for (int dt = 0; dt < 4; ++dt) b_cur[dt] = b_nxt[dt];
      }
    }
  }
#pragma unroll
  for (int m = 1; m <= 4; m <<= 1) {
    qsum += __shfl_xor(qsum, m, 64);
    asum += __shfl_xor(asum, m, 64);
  }
  if ((t & 7) == 0) { denom_s[sr] = qsum; deg_s[sr] = asum; }
  __syncthreads();
  if (t < BM) {
    const float dn = denom_s[t];
    coef_s[t] = dn > 0.f ? 0.5f * deg_s[t] / dn : 0.f;
  }
  __syncthreads();
#pragma unroll
  for (int f = 0; f < 2; ++f) {
#pragma unroll
    for (int dt = 0; dt < 4; ++dt) {
      const int col = d0 + dt * 16 + lrow;
#pragma unroll
      for (int g = 0; g < 4; ++g) {
        const int r = f * 16 + kgrp * 4 + g;
        out[(size_t)(i0 + r) * DD + col] =
            coef_s[r] * acc1[f][dt][g] + 0.5f * acc2[f][dt][g];
      }
    }
  }
}

extern "C" void kernel_launch(void* const* d_in, const int* in_sizes, int n_in,
                              void* d_out, int out_size, void* d_ws, size_t ws_size,
                              hipStream_t stream) {
  const float* h_eu = (const float*)d_in[0];
  const float* h_po = (const float*)d_in[1];
  const float* h_lo = (const float*)d_in[2];
  const float* adj  = (const float*)d_in[3];
  const float* a1   = (const float*)d_in[4];
  const float* a2   = (const float*)d_in[5];
  const float* a3   = (const float*)d_in[6];
  float* out = (float*)d_out;

  const size_t need_uv   = (size_t)2 * NN * 4;
  const size_t need_full = need_uv + (size_t)NN * DD * 2;  // 6,389,760 B
  float* u = (float*)d_ws;
  float* v = u + NN;
  unsigned short* h_poT = (unsigned short*)(v + NN);
  const bool big_ws = ws_size >= need_full;

  prep_uv<<<NN / 64, 256, 0, stream>>>(h_eu, h_po, h_lo, a1, a2, a3, u, v);
  if (big_ws) {
    prep_T<<<NN / 64, 256, 0, stream>>>(h_po, h_poT);
    fused2<<<NN / BM, 256, 0, stream>>>(adj, u, v, h_poT, out);
  } else {
    fused_kernel<false><<<NN / BM, 256, 0, stream>>>(adj, u, v, nullptr, h_po, out);
  }
}

// Round 4
// 678.786 us; speedup vs baseline: 1.3023x; 1.3023x over previous
//
#include <hip/hip_runtime.h>
#include <hip/hip_bf16.h>

// N=12288, D=256.
//   e[i,j] = lrelu(u[i] + v[j]);  u = h_eu@a1 + h_lo@a3, v = h_po@a2
//   q = exp2(e*log2e - SHIFT2) masked by adj>0 (constant shift; exp scale-free)
//   out_i = (0.5*deg_i/denom_i) * (q_i @ h_po) + 0.5 * (adj_i @ h_po)
//
// fused3: lane-local A scoring (no A-LDS, proven r3), B tile double-buffered
// in LDS (fixes r3's serialized L3-latency B loads), 1 barrier per 64-k step.

#define NN 12288
#define DD 256
#define BM 32
#define BKM 64                // macro k-step
#define STEPS (NN / BKM)      // 192
#define LDB 72                // padded ushort stride for B tile rows (144 B)
#define LOG2E 1.44269504f
#define SHIFT2 36.067376f     // 25*log2e

typedef __attribute__((ext_vector_type(8))) short s16x8;
typedef __attribute__((ext_vector_type(4))) float f32x4;

__device__ __forceinline__ unsigned short f2bf(float f) {
  unsigned u = __builtin_bit_cast(unsigned, f);
  u += 0x7FFFu + ((u >> 16) & 1u);
  return (unsigned short)(u >> 16);
}
__device__ __forceinline__ unsigned pack_bf2(float a, float b) {
  unsigned short lo = __builtin_bit_cast(unsigned short, __float2bfloat16(a));
  unsigned short hi = __builtin_bit_cast(unsigned short, __float2bfloat16(b));
  return (unsigned)lo | ((unsigned)hi << 16);
}
__device__ __forceinline__ float exp2_hw(float x) {
  float r;
  asm("v_exp_f32 %0, %1" : "=v"(r) : "v"(x));
  return r;
}

// ---------------- prep: u2, v2 (pre-scaled by log2e) ----------------
__global__ __launch_bounds__(256) void prep_uv(
    const float* __restrict__ h_eu, const float* __restrict__ h_po,
    const float* __restrict__ h_lo, const float* __restrict__ a1,
    const float* __restrict__ a2, const float* __restrict__ a3,
    float* __restrict__ u, float* __restrict__ v) {
  const int t = threadIdx.x;
  const int wave = t >> 6, lane = t & 63;
  const int r0 = blockIdx.x * 64;
  for (int rr = 0; rr < 16; ++rr) {
    const int row = r0 + wave * 16 + rr;
    const float* pe = h_eu + (size_t)row * DD;
    const float* pl = h_lo + (size_t)row * DD;
    const float* pp = h_po + (size_t)row * DD;
    float su = 0.f, sv = 0.f;
#pragma unroll
    for (int c = 0; c < 4; ++c) {
      const int d = lane + c * 64;
      su = fmaf(pe[d], a1[d], su);
      su = fmaf(pl[d], a3[d], su);
      sv = fmaf(pp[d], a2[d], sv);
    }
#pragma unroll
    for (int m = 32; m; m >>= 1) {
      su += __shfl_xor(su, m, 64);
      sv += __shfl_xor(sv, m, 64);
    }
    if (lane == 0) { u[row] = su * LOG2E; v[row] = sv * LOG2E; }
  }
}

// ---------------- prep: h_poT (bf16, [D][N]) ----------------
__global__ __launch_bounds__(256) void prep_T(
    const float* __restrict__ hpo, unsigned short* __restrict__ h_poT) {
  const int t = threadIdx.x;
  const int r0 = blockIdx.x * 64;
  unsigned short* dst = h_poT + (size_t)t * NN + r0;
#pragma unroll
  for (int c = 0; c < 16; ++c) {
    unsigned short x0 = f2bf(hpo[(size_t)(r0 + c * 4 + 0) * DD + t]);
    unsigned short x1 = f2bf(hpo[(size_t)(r0 + c * 4 + 1) * DD + t]);
    unsigned short x2 = f2bf(hpo[(size_t)(r0 + c * 4 + 2) * DD + t]);
    unsigned short x3 = f2bf(hpo[(size_t)(r0 + c * 4 + 3) * DD + t]);
    ((uint2*)dst)[c] = make_uint2((unsigned)x0 | ((unsigned)x1 << 16),
                                  (unsigned)x2 | ((unsigned)x3 << 16));
  }
}

// ---------------- fused3: lane-local A, LDS-dbuf B ----------------
__global__ __launch_bounds__(256, 2) void fused3(
    const float* __restrict__ adj, const float* __restrict__ u2,
    const float* __restrict__ v2, const unsigned short* __restrict__ h_poT,
    float* __restrict__ out) {
  __shared__ unsigned short bt[2][DD][LDB];  // 73,728 B (B-tile double buffer)
  __shared__ float denom_s[BM], deg_s[BM], coef_s[BM];

  const int t = threadIdx.x;
  const int wave = t >> 6, lane = t & 63;
  const int rf = wave & 1;       // rows rf*16..+16
  const int ks = wave >> 1;      // k-slice ks*32..+32 within macro-step
  const int lrow = lane & 15, kgrp = lane >> 4;
  const int i0 = blockIdx.x * BM;
  const int row = i0 + rf * 16 + lrow;

  if (t < BM) { denom_s[t] = 0.f; deg_s[t] = 0.f; }

  const float u_r = u2[row];

  // staging: thread t owns B row d=t (128 B per macro-step)
  const unsigned short* srow = h_poT + (size_t)t * NN;
  // lane-local adj/v addressing (k offset within macro-step: ks*32+kgrp*8)
  const float* aptr = adj + (size_t)row * NN + ks * 32 + kgrp * 8;
  const float* vptr = v2 + ks * 32 + kgrp * 8;

  f32x4 acc1[16] = {};  // q   @ B
  f32x4 acc2[16] = {};  // adj @ B
  float qsum = 0.f, asum = 0.f;

  // ---- prologue: stage tile 0, prefetch A/V for step 0 ----
  {
    uint4 st[8];
#pragma unroll
    for (int c = 0; c < 8; ++c) st[c] = ((const uint4*)srow)[c];
#pragma unroll
    for (int c = 0; c < 8; ++c) *(uint4*)&bt[0][t][c * 8] = st[c];
  }
  float4 A0 = *(const float4*)(aptr);
  float4 A1 = *(const float4*)(aptr + 4);
  float4 V0 = *(const float4*)(vptr);
  float4 V1 = *(const float4*)(vptr + 4);
  __syncthreads();

  for (int jt = 0; jt < STEPS; ++jt) {
    const int cur = jt & 1;
    const bool last = (jt + 1 == STEPS);
    const int jn = last ? 0 : (jt + 1) * BKM;  // wrap: loaded, never used

    // 1) staging loads for next tile (regs)
    uint4 st[8];
    {
      const uint4* s = (const uint4*)(srow + jn);
#pragma unroll
      for (int c = 0; c < 8; ++c) st[c] = s[c];
    }
    // 2) A/V prefetch for next step
    const float4 An0 = *(const float4*)(aptr + jn);
    const float4 An1 = *(const float4*)(aptr + jn + 4);
    const float4 Vn0 = *(const float4*)(vptr + jn);
    const float4 Vn1 = *(const float4*)(vptr + jn + 4);

    // 3) score this lane's 8 elements (A-fragment row)
    const float cf[8] = {A0.x, A0.y, A0.z, A0.w, A1.x, A1.y, A1.z, A1.w};
    const float vf[8] = {V0.x, V0.y, V0.z, V0.w, V1.x, V1.y, V1.z, V1.w};
    unsigned qp[4], app[4];
#pragma unroll
    for (int e = 0; e < 8; e += 2) {
      const float t0 = u_r + vf[e], t1 = u_r + vf[e + 1];
      const float x0 = fmaxf(t0, 0.01f * t0), x1 = fmaxf(t1, 0.01f * t1);
      float q0 = exp2_hw(x0 - SHIFT2), q1 = exp2_hw(x1 - SHIFT2);
      q0 = (cf[e] > 0.f) ? q0 : 0.f;
      q1 = (cf[e + 1] > 0.f) ? q1 : 0.f;
      qsum += q0; qsum += q1;
      asum += cf[e]; asum += cf[e + 1];
      qp[e >> 1] = pack_bf2(q0, q1);
      app[e >> 1] = pack_bf2(cf[e], cf[e + 1]);
    }
    const s16x8 qa = __builtin_bit_cast(s16x8, *(uint4*)qp);
    const s16x8 aa = __builtin_bit_cast(s16x8, *(uint4*)app);

    // 4) MFMAs, B from LDS
#pragma unroll
    for (int dt = 0; dt < 16; ++dt) {
      const s16x8 bb = *(const s16x8*)&bt[cur][dt * 16 + lrow][ks * 32 + kgrp * 8];
      acc1[dt] = __builtin_amdgcn_mfma_f32_16x16x32_bf16(qa, bb, acc1[dt], 0, 0, 0);
      acc2[dt] = __builtin_amdgcn_mfma_f32_16x16x32_bf16(aa, bb, acc2[dt], 0, 0, 0);
    }

    // 5) write next tile; rotate A/V
    if (!last) {
#pragma unroll
      for (int c = 0; c < 8; ++c) *(uint4*)&bt[cur ^ 1][t][c * 8] = st[c];
      A0 = An0; A1 = An1; V0 = Vn0; V1 = Vn1;
    }
    // 6) one barrier per macro-step (covers RAW on bt[cur^1], WAR on bt[cur])
    __syncthreads();
  }

  // ---- stats: reduce over kgrp, then LDS-atomic over the 2 kslices ----
  qsum += __shfl_xor(qsum, 16, 64); qsum += __shfl_xor(qsum, 32, 64);
  asum += __shfl_xor(asum, 16, 64); asum += __shfl_xor(asum, 32, 64);
  if (kgrp == 0) {
    atomicAdd(&denom_s[rf * 16 + lrow], qsum);
    atomicAdd(&deg_s[rf * 16 + lrow], asum);
  }
  __syncthreads();
  if (t < BM) {
    const float dn = denom_s[t];
    coef_s[t] = dn > 0.f ? 0.5f * deg_s[t] / dn : 0.f;
  }

  // ---- reduce acc over kslices via LDS (reuse bt, 32 KB needed) ----
  float* lred = (float*)bt;
  const int lbase = ((rf * 16) * 64 + lane) * 4;
  if (ks == 1) {
#pragma unroll
    for (int dt = 0; dt < 16; ++dt)
      *(f32x4*)&lred[lbase + dt * 256] = acc1[dt];
  }
  __syncthreads();
  if (ks == 0) {
#pragma unroll
    for (int dt = 0; dt < 16; ++dt)
      acc1[dt] += *(const f32x4*)&lred[lbase + dt * 256];
  }
  __syncthreads();
  if (ks == 1) {
#pragma unroll
    for (int dt = 0; dt < 16; ++dt)
      *(f32x4*)&lred[lbase + dt * 256] = acc2[dt];
  }
  __syncthreads();
  if (ks == 0) {
#pragma unroll
    for (int dt = 0; dt < 16; ++dt) {
      acc2[dt] += *(const f32x4*)&lred[lbase + dt * 256];
      const int col = dt * 16 + lrow;
#pragma unroll
      for (int g = 0; g < 4; ++g) {
        const int r = rf * 16 + kgrp * 4 + g;
        out[(size_t)(i0 + r) * DD + col] =
            coef_s[r] * acc1[dt][g] + 0.5f * acc2[dt][g];
      }
    }
  }
}

// ---------------- fallback (small ws): round-2 proven kernel ----------------
__global__ __launch_bounds__(256) void fused_fb(
    const float* __restrict__ adj, const float* __restrict__ u,
    const float* __restrict__ v, const float* __restrict__ hpo,
    float* __restrict__ out) {
#define LDA 40
  __shared__ unsigned short qlds[BM][LDA];
  __shared__ unsigned short alds[BM][LDA];
  __shared__ unsigned short btf[DD][LDA];
  __shared__ float denom_s[BM], deg_s[BM], coef_s[BM];

  const int t = threadIdx.x;
  const int wave = t >> 6, lane = t & 63;
  const int i0 = blockIdx.x * BM;
  const int sr = t >> 3;
  const int sc = (t & 7) * 4;
  const float u_r = u[i0 + sr];
  const int d0 = wave * 64;
  const int lrow = lane & 15;
  const int kgrp = lane >> 4;

  f32x4 acc1[2][4] = {};
  f32x4 acc2[2][4] = {};
  float qsum = 0.f, asum = 0.f;

  const float* arow = adj + (size_t)(i0 + sr) * NN + sc;
  float4 a_cur = *(const float4*)(arow);

  constexpr int NSTEP = NN / 32;
  for (int jt = 0; jt < NSTEP; ++jt) {
    const int j = jt * 32;
    float4 a_nxt;
    const bool has_next = (jt + 1 < NSTEP);
    if (has_next) a_nxt = *(const float4*)(arow + j + 32);
    const float4 vv = *(const float4*)(v + j + sc);
    unsigned short qb[4], ab[4];
    {
      const float aa4[4] = {a_cur.x, a_cur.y, a_cur.z, a_cur.w};
      const float vvv[4] = {vv.x, vv.y, vv.z, vv.w};
#pragma unroll
      for (int k = 0; k < 4; ++k) {
        const float a = aa4[k];
        const float s = u_r + vvv[k];
        const float x = fmaxf(s, 0.01f * s);
        const float q = (a > 0.f) ? exp2_hw(x - SHIFT2) : 0.f;
        qsum += q;
        asum += a;
        qb[k] = f2bf(q);
        ab[k] = f2bf(a);
      }
    }
    *(uint2*)&qlds[sr][sc] = make_uint2((unsigned)qb[0] | ((unsigned)qb[1] << 16),
                                        (unsigned)qb[2] | ((unsigned)qb[3] << 16));
    *(uint2*)&alds[sr][sc] = make_uint2((unsigned)ab[0] | ((unsigned)ab[1] << 16),
                                        (unsigned)ab[2] | ((unsigned)ab[3] << 16));
    {
      const int br = t >> 3;
      const float* src = hpo + (size_t)(j + br) * DD;
#pragma unroll
      for (int cc = 0; cc < 8; ++cc) {
        const int c = (t & 7) * 4 + cc * 32;
        const float4 hv = *(const float4*)(src + c);
        btf[c + 0][br] = f2bf(hv.x);
        btf[c + 1][br] = f2bf(hv.y);
        btf[c + 2][br] = f2bf(hv.z);
        btf[c + 3][br] = f2bf(hv.w);
      }
    }
    __syncthreads();

    const s16x8 qa0 = *(const s16x8*)&qlds[lrow][kgrp * 8];
    const s16x8 qa1 = *(const s16x8*)&qlds[16 + lrow][kgrp * 8];
    const s16x8 ad0 = *(const s16x8*)&alds[lrow][kgrp * 8];
    const s16x8 ad1 = *(const s16x8*)&alds[16 + lrow][kgrp * 8];
#pragma unroll
    for (int dt = 0; dt < 4; ++dt) {
      const s16x8 b = *(const s16x8*)&btf[d0 + dt * 16 + lrow][kgrp * 8];
      acc1[0][dt] = __builtin_amdgcn_mfma_f32_16x16x32_bf16(qa0, b, acc1[0][dt], 0, 0, 0);
      acc1[1][dt] = __builtin_amdgcn_mfma_f32_16x16x32_bf16(qa1, b, acc1[1][dt], 0, 0, 0);
      acc2[0][dt] = __builtin_amdgcn_mfma_f32_16x16x32_bf16(ad0, b, acc2[0][dt], 0, 0, 0);
      acc2[1][dt] = __builtin_amdgcn_mfma_f32_16x16x32_bf16(ad1, b, acc2[1][dt], 0, 0, 0);
    }
    __syncthreads();
    if (has_next) a_cur = a_nxt;
  }
#pragma unroll
  for (int m = 1; m <= 4; m <<= 1) {
    qsum += __shfl_xor(qsum, m, 64);
    asum += __shfl_xor(asum, m, 64);
  }
  if ((t & 7) == 0) { denom_s[sr] = qsum; deg_s[sr] = asum; }
  __syncthreads();
  if (t < BM) {
    const float dn = denom_s[t];
    coef_s[t] = dn > 0.f ? 0.5f * deg_s[t] / dn : 0.f;
  }
  __syncthreads();
#pragma unroll
  for (int f = 0; f < 2; ++f) {
#pragma unroll
    for (int dt = 0; dt < 4; ++dt) {
      const int col = d0 + dt * 16 + lrow;
#pragma unroll
      for (int g = 0; g < 4; ++g) {
        const int r = f * 16 + kgrp * 4 + g;
        out[(size_t)(i0 + r) * DD + col] =
            coef_s[r] * acc1[f][dt][g] + 0.5f * acc2[f][dt][g];
      }
    }
  }
}

extern "C" void kernel_launch(void* const* d_in, const int* in_sizes, int n_in,
                              void* d_out, int out_size, void* d_ws, size_t ws_size,
                              hipStream_t stream) {
  const float* h_eu = (const float*)d_in[0];
  const float* h_po = (const float*)d_in[1];
  const float* h_lo = (const float*)d_in[2];
  const float* adj  = (const float*)d_in[3];
  const float* a1   = (const float*)d_in[4];
  const float* a2   = (const float*)d_in[5];
  const float* a3   = (const float*)d_in[6];
  float* out = (float*)d_out;

  const size_t need_uv   = (size_t)2 * NN * 4;
  const size_t need_full = need_uv + (size_t)NN * DD * 2;  // 6,389,760 B
  float* u = (float*)d_ws;
  float* v = u + NN;
  unsigned short* h_poT = (unsigned short*)(v + NN);
  const bool big_ws = ws_size >= need_full;

  prep_uv<<<NN / 64, 256, 0, stream>>>(h_eu, h_po, h_lo, a1, a2, a3, u, v);
  if (big_ws) {
    prep_T<<<NN / 64, 256, 0, stream>>>(h_po, h_poT);
    fused3<<<NN / BM, 256, 0, stream>>>(adj, u, v, h_poT, out);
  } else {
    fused_fb<<<NN / BM, 256, 0, stream>>>(adj, u, v, h_po, out);
  }
}